// Round 7
// baseline (285.625 us; speedup 1.0000x reference)
//
#include <hip/hip_runtime.h>
#include <hip/hip_bf16.h>
#include <hip/hip_fp16.h>

typedef unsigned short u16;
typedef signed char s8;
typedef __attribute__((ext_vector_type(8))) short short8;
typedef __attribute__((ext_vector_type(4))) float f32x4;
typedef __attribute__((ext_vector_type(4))) int i32x4;

#define NELEM 524288          // 8*64*32*32
#define PADW 34
#define PLANE 73984           // 34*34*64 elements per padded image
#define SEQ 32

__device__ inline void split3(float v, u16& a, u16& b, u16& c) {
  __hip_bfloat16 h1 = __float2bfloat16(v);
  float r1 = v - __bfloat162float(h1);
  __hip_bfloat16 h2 = __float2bfloat16(r1);
  float r2 = r1 - __bfloat162float(h2);
  __hip_bfloat16 h3 = __float2bfloat16(r2);
  a = *reinterpret_cast<u16*>(&h1);
  b = *reinterpret_cast<u16*>(&h2);
  c = *reinterpret_cast<u16*>(&h3);
}

__device__ inline void gload16(const void* g, void* l) {
  typedef const __attribute__((address_space(1))) void* gp_t;
  typedef __attribute__((address_space(3))) void* lp_t;
  __builtin_amdgcn_global_load_lds((gp_t)g, (lp_t)l, 16, 0, 0);
}

// Constant-current LIF encoder in f64 over the PADDED plane (borders write 0).
// x(t) i8 exact 0/1, layout xp[t][b][py][px][c].
__global__ void encode_kernel(const float* __restrict__ input, s8* __restrict__ xp) {
  int e = blockIdx.x * 256 + threadIdx.x;   // (b*1156 + pp)*64 + c ; 8*1156*64 total
  int c = e & 63;
  int pp = (e >> 6) % 1156;
  int b = e / (1156 * 64);
  int py = pp / 34, px = pp - py * 34;
  size_t base = (size_t)b * PLANE + (size_t)pp * 64 + c;
  bool interior = (py >= 1 && py <= 32 && px >= 1 && px <= 32);
  const double DMI = 0.001 * 100.0;
  double inp = interior ? (double)input[(size_t)(((b << 6) + c) << 10) + (py - 1) * 32 + (px - 1)] : 0.0;
  double ve = 0.0;
  for (int t = 0; t < SEQ; ++t) {
    double v = ve + DMI * (inp - ve);
    bool x = interior && (v > 1.0);
    ve = x ? 0.0 : v;
    xp[(size_t)t * (8 * PLANE) + base] = x ? (s8)1 : (s8)0;
  }
}

// h0 / c0 -> padded channel-last, 3-way bf16 split; covers pad region with zeros.
__global__ void prep_hc_kernel(const float* __restrict__ h0, const float* __restrict__ c0,
                               u16* __restrict__ h1, u16* __restrict__ h2, u16* __restrict__ h3,
                               u16* __restrict__ c1, u16* __restrict__ c2, u16* __restrict__ c3) {
  int e = blockIdx.x * 256 + threadIdx.x;   // (b*1156 + pp)*64 + c
  int c = e & 63;
  int pp = (e >> 6) % 1156;
  int b = e / (1156 * 64);
  int py = pp / 34, px = pp - py * 34;
  size_t dst = (size_t)b * PLANE + (size_t)pp * 64 + c;
  bool interior = (py >= 1 && py <= 32 && px >= 1 && px <= 32);
  u16 a = 0, bb = 0, cc = 0, d = 0, ee = 0, ff = 0;
  if (interior) {
    size_t src = (size_t)(((b << 6) + c) << 10) + (py - 1) * 32 + (px - 1);
    split3(h0[src], a, bb, cc);
    split3(c0[src], d, ee, ff);
  }
  h1[dst] = a; h2[dst] = bb; h3[dst] = cc;
  c1[dst] = d; c2[dst] = ee; c3[dst] = ff;
}

// Weights: ih -> EXACT 24-bit fixed point, 3 signed-byte parts:
//   W24 = round(w*2^28) (|W24| < 2^23 since |w| <= 1/48), W24 = b2*2^16 + b1*2^8 + b0.
// hh/ch -> bf16 3-part. o-gate rows are dead.
__global__ void prep_w_kernel(const float* __restrict__ wih, const float* __restrict__ whh,
                              const float* __restrict__ wch,
                              s8* __restrict__ iq0, s8* __restrict__ iq1, s8* __restrict__ iq2,
                              u16* __restrict__ hh1, u16* __restrict__ hh2, u16* __restrict__ hh3,
                              u16* __restrict__ ch1, u16* __restrict__ ch2, u16* __restrict__ ch3) {
  int t = blockIdx.x * 256 + threadIdx.x;   // (tap*512 + row)*64 + c
  int c = t & 63;
  int row = (t >> 6) & 511;
  int tap = t >> 15;
  if (row < 192) {
    float v = wih[(size_t)((row << 6) + c) * 9 + tap];
    int Wi = (int)llrint((double)v * 268435456.0);
    int b0 = (Wi << 24) >> 24;
    int W1 = (Wi - b0) >> 8;
    int b1 = (W1 << 24) >> 24;
    int b2 = (W1 - b1) >> 8;
    size_t d = (size_t)(tap * 192 + row) * 64 + c;
    iq0[d] = (s8)b0; iq1[d] = (s8)b1; iq2[d] = (s8)b2;
  } else {
    const float* src; u16 *d1, *d2, *d3; int m, Mtot;
    if (row < 384) { src = whh; m = row - 192; Mtot = 192; d1 = hh1; d2 = hh2; d3 = hh3; }
    else           { src = wch; m = row - 384; Mtot = 128; d1 = ch1; d2 = ch2; d3 = ch3; }
    float v = src[(size_t)((m << 6) + c) * 9 + tap];
    u16 a, b, cc; split3(v, a, b, cc);
    size_t d = (size_t)(tap * Mtot + m) * 64 + c;
    d1[d] = a; d2[d] = b; d3[d] = cc;
  }
}

// FUSED conv(x,W_ih) + LIF scan over all 32 timesteps.
// Grid (6,16,8): x = gate*2+mhalf, y = rg (2 image rows), z = b.
// Block 256 thr = 4 waves (2m x 2n). Block tile: 32 m-rows (one gate half) x 64 px.
// Wave: 16m x 32px -> fm=1, fn=2. Per thread: 8 output elements.
// LIF state lives in REGISTERS across t: v,cur (f64), mx,mo (f32). No wx buffer.
// t processed in chunks of 2; acc[t2][part][fn] i32 exact; W tap-tiles double-
// buffered from L2; X planes quad-buffered with prefetch spread over taps.
__global__ __launch_bounds__(256, 2) void fused_kernel(
    const s8* __restrict__ X, const s8* __restrict__ W0p, const s8* __restrict__ W1p,
    const s8* __restrict__ W2p,
    const float* __restrict__ whb, const float* __restrict__ wcb,
    const float* __restrict__ bih, const float* __restrict__ bhh,
    const float* __restrict__ bch, float* __restrict__ maxbuf) {
  __shared__ uint4 ldsx4[4 * 544];   // 4 X plane slots x 8704 B
  __shared__ uint4 ldsw4[2 * 384];   // W dbuf x (3 parts x 2048 B)
  char* ldsx = (char*)ldsx4;
  char* ldsw = (char*)ldsw4;

  const double DMI = 0.001 * 100.0;
  const double DSI = 0.001 * 200.0;
  const double S0 = 1.0 / 268435456.0;   // 2^-28

  const int tid = threadIdx.x;
  const int lane = tid & 63;
  const int wid = tid >> 6;
  const int bx = blockIdx.x;
  const int gate = bx >> 1, mh = bx & 1;
  const int rg = blockIdx.y;
  const int b = blockIdx.z;
  const int wm = wid >> 1, wn = wid & 1;
  const int kg = lane >> 4;

  const s8* wps[3] = {W0p, W1p, W2p};
  const int wrow0 = gate * 64 + mh * 32;

  auto xsrc = [&](int t) {
    return (const char*)X + (size_t)(t * 8 + b) * PLANE + (size_t)rg * 2 * (PADW * 64);
  };
  auto stageW = [&](int tap, int buf) {
    {
      int part = tid >> 7;            // granules 0-255 -> parts 0,1
      int Lb = (tid & 127) << 4;
      const char* g = (const char*)wps[part] + ((size_t)tap * 192 + wrow0) * 64
                      + (Lb ^ (((Lb >> 7) & 3) << 4));
      gload16(g, ldsw + buf * 6144 + part * 2048 + Lb);
    }
    if (tid < 128) {                  // part 2
      int Lb = tid << 4;
      const char* g = (const char*)wps[2] + ((size_t)tap * 192 + wrow0) * 64
                      + (Lb ^ (((Lb >> 7) & 3) << 4));
      gload16(g, ldsw + buf * 6144 + 2 * 2048 + Lb);
    }
  };
  auto stageX = [&](int t) {
    const char* src = xsrc(t);
    char* dst = ldsx + (t & 3) * 8704;
    for (int q = tid; q < 544; q += 256) {
      int L = q << 4;
      gload16(src + (L ^ (((L >> 7) & 3) << 4)), dst + L);
    }
  };

  // ---- per-element constants & state init ----
  const int cbase = mh * 32 + wm * 16 + (lane >> 4) * 4;   // + r
  const int hwbase = rg * 64 + wn * 32 + (lane & 15);      // + fn*16
  double cterm[8], v[8], cur[8];
  float mx[8], mo[8];
#pragma unroll
  for (int fn = 0; fn < 2; ++fn)
#pragma unroll
    for (int r = 0; r < 4; ++r) {
      int el = fn * 4 + r;
      int row = gate * 64 + cbase + r;
      int hw = hwbase + fn * 16;
      double cI = (double)whb[((size_t)b * 192 + row) * 1024 + hw] + (double)bhh[row];
      if (gate < 2)
        cI = cI + ((double)wcb[((size_t)b * 128 + row) * 1024 + hw] + (double)bch[row]);
      cterm[el] = (double)bih[row] + cI;
      v[el] = 0.0; cur[el] = 0.0; mx[el] = -INFINITY; mo[el] = -INFINITY;
    }

  i32x4 acc[2][3][2];
#pragma unroll
  for (int t2 = 0; t2 < 2; ++t2)
#pragma unroll
    for (int p = 0; p < 3; ++p)
#pragma unroll
      for (int fn = 0; fn < 2; ++fn)
#pragma unroll
        for (int k = 0; k < 4; ++k) acc[t2][p][fn][k] = 0;

  stageX(0); stageX(1); stageW(0, 0);
  __syncthreads();
  int wbuf = 0;

  for (int tc = 0; tc < 16; ++tc) {
#pragma unroll
    for (int tap = 0; tap < 9; ++tap) {
      if (!(tc == 15 && tap == 8)) stageW(tap == 8 ? 0 : tap + 1, wbuf ^ 1);
      if (tc < 15 && tap < 8 && tid < 136) {   // spread X prefetch over 8 taps
        int gq = tap * 136 + tid;              // 0..1087 over 2 planes x 544
        int pl = gq >= 544;
        int tn = 2 * tc + 2 + pl;
        int L = (gq - pl * 544) << 4;
        gload16(xsrc(tn) + (L ^ (((L >> 7) & 3) << 4)), ldsx + (tn & 3) * 8704 + L);
      }
      const int kh = tap / 3, kw = tap - (tap / 3) * 3;
      char* wb = ldsw + wbuf * 6144;
      i32x4 af[3];
#pragma unroll
      for (int p = 0; p < 3; ++p) {
        int m = wm * 16 + (lane & 15);
        int byte = (m * 64 + kg * 16) ^ (((m >> 1) & 3) << 4);
        af[p] = *reinterpret_cast<const i32x4*>(wb + p * 2048 + byte);
      }
#pragma unroll
      for (int t2 = 0; t2 < 2; ++t2) {
        const char* xpl = ldsx + ((2 * tc + t2) & 3) * 8704;
        i32x4 bfr[2];
#pragma unroll
        for (int fn = 0; fn < 2; ++fn) {
          int p = wn * 32 + fn * 16 + (lane & 15);
          int pL = ((p >> 5) + kh) * PADW + (p & 31) + kw;
          int byte = (pL * 64 + kg * 16) ^ (((pL >> 1) & 3) << 4);
          bfr[fn] = *reinterpret_cast<const i32x4*>(xpl + byte);
        }
        __builtin_amdgcn_s_setprio(1);
#pragma unroll
        for (int p = 0; p < 3; ++p)
#pragma unroll
          for (int fn = 0; fn < 2; ++fn)
            acc[t2][p][fn] = __builtin_amdgcn_mfma_i32_16x16x64_i8(af[p], bfr[fn], acc[t2][p][fn], 0, 0, 0);
        __builtin_amdgcn_s_setprio(0);
      }
      __syncthreads();
      wbuf ^= 1;
    }
    // ---- LIF update for t = 2tc, 2tc+1 (exact i32 recombine, f64 states) ----
#pragma unroll
    for (int t2 = 0; t2 < 2; ++t2) {
      int t = 2 * tc + t2;
#pragma unroll
      for (int fn = 0; fn < 2; ++fn)
#pragma unroll
        for (int r = 0; r < 4; ++r) {
          int el = fn * 4 + r;
          int a0 = acc[t2][0][fn][r], a1 = acc[t2][1][fn][r], a2 = acc[t2][2][fn][r];
          double wx = ((double)a2 * 65536.0 + (double)(a1 * 256 + a0)) * S0;
          double inp = wx + cterm[el];
          double vd = v[el] + DMI * (cur[el] - v[el]);   // OLD current
          double vnew = (vd > 1.0) ? 0.0 : vd;
          v[el] = vnew;
          cur[el] = (cur[el] - DSI * cur[el]) + inp;
          if (gate == 2) {
            double vod = vnew + DMI * (cur[el] - vnew);  // o-gate from UPDATED g
            double vo = (vod > 1.0) ? 0.0 : vod;
            if (t >= 1) mo[el] = fmaxf(mo[el], (float)vo);
          }
          if (t >= 1) mx[el] = fmaxf(mx[el], (float)vnew);
        }
#pragma unroll
      for (int p = 0; p < 3; ++p)
#pragma unroll
        for (int fn = 0; fn < 2; ++fn)
#pragma unroll
          for (int k = 0; k < 4; ++k) acc[t2][p][fn][k] = 0;
    }
  }

  // ---- write per-gate maxima ----
#pragma unroll
  for (int fn = 0; fn < 2; ++fn)
#pragma unroll
    for (int r = 0; r < 4; ++r) {
      int el = fn * 4 + r;
      size_t e = ((size_t)b * 64 + cbase + r) * 1024 + hwbase + fn * 16;
      maxbuf[(size_t)gate * NELEM + e] = mx[el];
      if (gate == 2) maxbuf[(size_t)3 * NELEM + e] = mo[el];
    }
}

// wh + wc conv merged: bf16 3-plane x 3-part, 6 cross terms (unchanged).
__global__ __launch_bounds__(256) void conv1_kernel(
    const u16* __restrict__ Ah0, const u16* __restrict__ Ah1, const u16* __restrict__ Ah2,
    const u16* __restrict__ Ac0, const u16* __restrict__ Ac1, const u16* __restrict__ Ac2,
    const u16* __restrict__ Wh0, const u16* __restrict__ Wh1, const u16* __restrict__ Wh2,
    const u16* __restrict__ Wc0, const u16* __restrict__ Wc1, const u16* __restrict__ Wc2,
    float* __restrict__ outh, float* __restrict__ outc) {
  __shared__ uint4 ldsx4[3 * 1088];   // per plane: 4 rows x 34 px x 128 B
  __shared__ uint4 ldsw4[3 * 512];    // single buffer: 3 parts x 8 KB
  char* ldsx = (char*)ldsx4;
  char* ldsw = (char*)ldsw4;

  const int tid = threadIdx.x;
  const int lane = tid & 63;
  const int wid = tid >> 6;
  const bool isC = blockIdx.x >= 3;
  const int mtile = isC ? blockIdx.x - 3 : blockIdx.x;
  const int Mtot = isC ? 128 : 192;
  const int rg = blockIdx.y;          // 0..15 (2 px-rows each)
  const int img = blockIdx.z;
  const u16* aps[3] = {isC ? Ac0 : Ah0, isC ? Ac1 : Ah1, isC ? Ac2 : Ah2};
  const u16* wps[3] = {isC ? Wc0 : Wh0, isC ? Wc1 : Wh1, isC ? Wc2 : Wh2};
  float* out = isC ? outc : outh;

  {
    size_t abase = (size_t)img * PLANE + (size_t)rg * 2 * (PADW * 64);
#pragma unroll
    for (int pl = 0; pl < 3; ++pl) {
      const char* src = (const char*)(aps[pl] + abase);
      for (int q = tid; q < 1088; q += 256) {
        int L = q << 4;
        gload16(src + (L ^ (((L >> 7) & 7) << 4)), ldsx + pl * 17408 + L);
      }
    }
  }

  const size_t wrowbase = (size_t)mtile * 64 * 64;
  auto stageW = [&](int tap) {
#pragma unroll
    for (int part = 0; part < 3; ++part) {
      const char* gsrc = (const char*)(wps[part] + (size_t)tap * Mtot * 64 + wrowbase);
#pragma unroll
      for (int half = 0; half < 2; ++half) {
        int L = half * 4096 + tid * 16;
        gload16(gsrc + (L ^ (((L >> 7) & 7) << 4)), ldsw + part * 8192 + L);
      }
    }
  };

  f32x4 acc[2][2];
#pragma unroll
  for (int i = 0; i < 2; ++i)
#pragma unroll
    for (int j = 0; j < 2; ++j)
#pragma unroll
      for (int k = 0; k < 4; ++k) acc[i][j][k] = 0.f;

  const int wm = wid >> 1, wn = wid & 1;

  for (int tap = 0; tap < 9; ++tap) {
    if (tap) __syncthreads();
    stageW(tap);
    __syncthreads();
    const int kh = tap / 3, kw = tap - kh * 3;
#pragma unroll
    for (int khalf = 0; khalf < 2; ++khalf) {
      short8 af[3][2];
#pragma unroll
      for (int part = 0; part < 3; ++part)
#pragma unroll
        for (int fm = 0; fm < 2; ++fm) {
          int m = wm * 32 + fm * 16 + (lane & 15);
          int byte = (m * 128 + khalf * 64 + (lane >> 4) * 16) ^ ((m & 7) << 4);
          af[part][fm] = *reinterpret_cast<const short8*>(ldsw + part * 8192 + byte);
        }
#pragma unroll
      for (int pl = 0; pl < 3; ++pl) {
        short8 bfr[2];
#pragma unroll
        for (int fn = 0; fn < 2; ++fn) {
          int p = wn * 32 + fn * 16 + (lane & 15);
          int r = p >> 5, w = p & 31;
          int pL = (r + kh) * PADW + (w + kw);
          int byte = (pL * 128 + khalf * 64 + (lane >> 4) * 16) ^ ((pL & 7) << 4);
          bfr[fn] = *reinterpret_cast<const short8*>(ldsx + pl * 17408 + byte);
        }
        constexpr int npt[3] = {3, 2, 1};
        __builtin_amdgcn_s_setprio(1);
#pragma unroll
        for (int part = 0; part < 3; ++part) {
          if (part < npt[pl]) {
#pragma unroll
            for (int fm = 0; fm < 2; ++fm)
#pragma unroll
              for (int fn = 0; fn < 2; ++fn)
                acc[fm][fn] = __builtin_amdgcn_mfma_f32_16x16x32_bf16(af[part][fm], bfr[fn], acc[fm][fn], 0, 0, 0);
          }
        }
        __builtin_amdgcn_s_setprio(0);
      }
    }
  }

  size_t obase = (size_t)img * Mtot * 1024;
#pragma unroll
  for (int fm = 0; fm < 2; ++fm)
#pragma unroll
    for (int fn = 0; fn < 2; ++fn) {
      int pcol = rg * 64 + wn * 32 + fn * 16 + (lane & 15);
      int mrow0 = mtile * 64 + wm * 32 + fm * 16 + (lane >> 4) * 4;
#pragma unroll
      for (int r2 = 0; r2 < 4; ++r2)
        out[obase + (size_t)(mrow0 + r2) * 1024 + pcol] = acc[fm][fn][r2];
    }
}

__global__ void final_kernel(const float* __restrict__ maxbuf, const float* __restrict__ c0,
                             float* __restrict__ out) {
  int e = blockIdx.x * 256 + threadIdx.x;
  double mi = (double)maxbuf[e];
  double mf = (double)maxbuf[NELEM + e];
  double mg = (double)maxbuf[2 * (size_t)NELEM + e];
  double mo = (double)maxbuf[3 * (size_t)NELEM + e];
  double c1 = mf * (double)c0[e] + mi * mg;
  out[e] = (float)(mo * tanh(c1));
  out[NELEM + e] = (float)c1;
}

extern "C" void kernel_launch(void* const* d_in, const int* in_sizes, int n_in,
                              void* d_out, int out_size, void* d_ws, size_t ws_size,
                              hipStream_t stream) {
  const float* input = (const float*)d_in[0];
  const float* h0    = (const float*)d_in[1];
  const float* c0    = (const float*)d_in[2];
  const float* wih   = (const float*)d_in[3];
  const float* whh   = (const float*)d_in[4];
  const float* wch   = (const float*)d_in[5];
  const float* bih   = (const float*)d_in[6];
  const float* bhh   = (const float*)d_in[7];
  const float* bch   = (const float*)d_in[8];
  char* ws = (char*)d_ws;

  size_t off = 0;
  auto take = [&](size_t bytes) { size_t o = off; off += (bytes + 255) & ~(size_t)255; return o; };
  size_t oXp  = take((size_t)SEQ * 8 * PLANE);          // i8 spikes, 18.9 MB
  size_t oH1  = take((size_t)8 * PLANE * 2);
  size_t oH2  = take((size_t)8 * PLANE * 2);
  size_t oH3  = take((size_t)8 * PLANE * 2);
  size_t oC1  = take((size_t)8 * PLANE * 2);
  size_t oC2  = take((size_t)8 * PLANE * 2);
  size_t oC3  = take((size_t)8 * PLANE * 2);
  size_t oIq0 = take((size_t)9 * 192 * 64);             // i8 weight parts
  size_t oIq1 = take((size_t)9 * 192 * 64);
  size_t oIq2 = take((size_t)9 * 192 * 64);
  size_t oHh1 = take((size_t)9 * 192 * 64 * 2);
  size_t oHh2 = take((size_t)9 * 192 * 64 * 2);
  size_t oHh3 = take((size_t)9 * 192 * 64 * 2);
  size_t oCh1 = take((size_t)9 * 128 * 64 * 2);
  size_t oCh2 = take((size_t)9 * 128 * 64 * 2);
  size_t oCh3 = take((size_t)9 * 128 * 64 * 2);
  size_t oWh  = take((size_t)8 * 192 * 1024 * 4);
  size_t oWc  = take((size_t)8 * 128 * 1024 * 4);
  size_t oMx  = take((size_t)4 * NELEM * 4);            // maxima planes

  s8* xp   = (s8*)(ws + oXp);
  u16* h1p = (u16*)(ws + oH1); u16* h2p = (u16*)(ws + oH2); u16* h3p = (u16*)(ws + oH3);
  u16* c1p = (u16*)(ws + oC1); u16* c2p = (u16*)(ws + oC2); u16* c3p = (u16*)(ws + oC3);
  s8* iq0  = (s8*)(ws + oIq0); s8* iq1 = (s8*)(ws + oIq1); s8* iq2 = (s8*)(ws + oIq2);
  u16* hh1 = (u16*)(ws + oHh1); u16* hh2 = (u16*)(ws + oHh2); u16* hh3 = (u16*)(ws + oHh3);
  u16* ch1 = (u16*)(ws + oCh1); u16* ch2 = (u16*)(ws + oCh2); u16* ch3 = (u16*)(ws + oCh3);
  float* whb = (float*)(ws + oWh);
  float* wcb = (float*)(ws + oWc);
  float* mxb = (float*)(ws + oMx);

  encode_kernel<<<2312, 256, 0, stream>>>(input, xp);
  prep_hc_kernel<<<2312, 256, 0, stream>>>(h0, c0, h1p, h2p, h3p, c1p, c2p, c3p);
  prep_w_kernel<<<1152, 256, 0, stream>>>(wih, whh, wch, iq0, iq1, iq2,
                                          hh1, hh2, hh3, ch1, ch2, ch3);

  conv1_kernel<<<dim3(5, 16, 8), 256, 0, stream>>>(
      h1p, h2p, h3p, c1p, c2p, c3p,
      hh1, hh2, hh3, ch1, ch2, ch3, whb, wcb);

  fused_kernel<<<dim3(6, 16, 8), 256, 0, stream>>>(
      xp, iq0, iq1, iq2, whb, wcb, bih, bhh, bch, mxb);

  final_kernel<<<2048, 256, 0, stream>>>(mxb, c0, (float*)d_out);
}

// Round 8
// 200.132 us; speedup vs baseline: 1.4272x; 1.4272x over previous
//
#include <hip/hip_runtime.h>
#include <hip/hip_bf16.h>
#include <hip/hip_fp16.h>

typedef unsigned short u16;
typedef signed char s8;
typedef __attribute__((ext_vector_type(8))) short short8;
typedef __attribute__((ext_vector_type(4))) float f32x4;
typedef __attribute__((ext_vector_type(4))) int i32x4;

#define NELEM 524288          // 8*64*32*32
#define PADW 34
#define PLANE 73984           // 34*34*64 elements per padded image
#define SEQ 32

__device__ inline void split3(float v, u16& a, u16& b, u16& c) {
  __hip_bfloat16 h1 = __float2bfloat16(v);
  float r1 = v - __bfloat162float(h1);
  __hip_bfloat16 h2 = __float2bfloat16(r1);
  float r2 = r1 - __bfloat162float(h2);
  __hip_bfloat16 h3 = __float2bfloat16(r2);
  a = *reinterpret_cast<u16*>(&h1);
  b = *reinterpret_cast<u16*>(&h2);
  c = *reinterpret_cast<u16*>(&h3);
}

__device__ inline void gload16(const void* g, void* l) {
  typedef const __attribute__((address_space(1))) void* gp_t;
  typedef __attribute__((address_space(3))) void* lp_t;
  __builtin_amdgcn_global_load_lds((gp_t)g, (lp_t)l, 16, 0, 0);
}

// Constant-current LIF encoder in f64 over the PADDED plane (borders write 0).
// x(t) i8 exact 0/1, layout xp[t][b][py][px][c].
__global__ void encode_kernel(const float* __restrict__ input, s8* __restrict__ xp) {
  int e = blockIdx.x * 256 + threadIdx.x;   // (b*1156 + pp)*64 + c ; 8*1156*64 total
  int c = e & 63;
  int pp = (e >> 6) % 1156;
  int b = e / (1156 * 64);
  int py = pp / 34, px = pp - py * 34;
  size_t base = (size_t)b * PLANE + (size_t)pp * 64 + c;
  bool interior = (py >= 1 && py <= 32 && px >= 1 && px <= 32);
  const double DMI = 0.001 * 100.0;
  double inp = interior ? (double)input[(size_t)(((b << 6) + c) << 10) + (py - 1) * 32 + (px - 1)] : 0.0;
  double ve = 0.0;
  for (int t = 0; t < SEQ; ++t) {
    double v = ve + DMI * (inp - ve);
    bool x = interior && (v > 1.0);
    ve = x ? 0.0 : v;
    xp[(size_t)t * (8 * PLANE) + base] = x ? (s8)1 : (s8)0;
  }
}

// h0 / c0 -> padded channel-last, 3-way bf16 split; covers pad region with zeros.
__global__ void prep_hc_kernel(const float* __restrict__ h0, const float* __restrict__ c0,
                               u16* __restrict__ h1, u16* __restrict__ h2, u16* __restrict__ h3,
                               u16* __restrict__ c1, u16* __restrict__ c2, u16* __restrict__ c3) {
  int e = blockIdx.x * 256 + threadIdx.x;   // (b*1156 + pp)*64 + c
  int c = e & 63;
  int pp = (e >> 6) % 1156;
  int b = e / (1156 * 64);
  int py = pp / 34, px = pp - py * 34;
  size_t dst = (size_t)b * PLANE + (size_t)pp * 64 + c;
  bool interior = (py >= 1 && py <= 32 && px >= 1 && px <= 32);
  u16 a = 0, bb = 0, cc = 0, d = 0, ee = 0, ff = 0;
  if (interior) {
    size_t src = (size_t)(((b << 6) + c) << 10) + (py - 1) * 32 + (px - 1);
    split3(h0[src], a, bb, cc);
    split3(c0[src], d, ee, ff);
  }
  h1[dst] = a; h2[dst] = bb; h3[dst] = cc;
  c1[dst] = d; c2[dst] = ee; c3[dst] = ff;
}

// Weights: ih -> EXACT 24-bit fixed point, 3 signed-byte parts:
//   W24 = round(w*2^28) (|W24| < 2^23 since |w| <= 1/48), W24 = b2*2^16 + b1*2^8 + b0.
// hh/ch -> bf16 3-part. o-gate rows are dead.
__global__ void prep_w_kernel(const float* __restrict__ wih, const float* __restrict__ whh,
                              const float* __restrict__ wch,
                              s8* __restrict__ iq0, s8* __restrict__ iq1, s8* __restrict__ iq2,
                              u16* __restrict__ hh1, u16* __restrict__ hh2, u16* __restrict__ hh3,
                              u16* __restrict__ ch1, u16* __restrict__ ch2, u16* __restrict__ ch3) {
  int t = blockIdx.x * 256 + threadIdx.x;   // (tap*512 + row)*64 + c
  int c = t & 63;
  int row = (t >> 6) & 511;
  int tap = t >> 15;
  if (row < 192) {
    float v = wih[(size_t)((row << 6) + c) * 9 + tap];
    int Wi = (int)llrint((double)v * 268435456.0);
    int b0 = (Wi << 24) >> 24;
    int W1 = (Wi - b0) >> 8;
    int b1 = (W1 << 24) >> 24;
    int b2 = (W1 - b1) >> 8;
    size_t d = (size_t)(tap * 192 + row) * 64 + c;
    iq0[d] = (s8)b0; iq1[d] = (s8)b1; iq2[d] = (s8)b2;
  } else {
    const float* src; u16 *d1, *d2, *d3; int m, Mtot;
    if (row < 384) { src = whh; m = row - 192; Mtot = 192; d1 = hh1; d2 = hh2; d3 = hh3; }
    else           { src = wch; m = row - 384; Mtot = 128; d1 = ch1; d2 = ch2; d3 = ch3; }
    float v = src[(size_t)((m << 6) + c) * 9 + tap];
    u16 a, b, cc; split3(v, a, b, cc);
    size_t d = (size_t)(tap * Mtot + m) * 64 + c;
    d1[d] = a; d2[d] = b; d3[d] = cc;
  }
}

// FUSED conv(x,W_ih) + LIF scan, v2.
// Grid (12,8,8): x = gate*4+mq (16-row quad), y = rg (4 image rows), z = b.
// Block 256 thr = 4 waves (wn = n-tile of 32 px). Block tile: 16 m x 128 px.
// W resident in LDS (27.6 KB, staged ONCE); X 2 slots x 13056 B; 53.8 KB total
// -> 3 blocks/CU = 12 waves/CU; grid 768 = 3*256 exactly balanced.
// Per 2-t round: 9 taps x (3 af + 4 bfr ds_reads, 12 MFMA); barrier; X prefetch
// issue; LIF f64 update (hides prefetch latency); barrier. 32 barriers total.
__global__ __launch_bounds__(256, 3) void fused_kernel(
    const s8* __restrict__ X, const s8* __restrict__ W0p, const s8* __restrict__ W1p,
    const s8* __restrict__ W2p,
    const float* __restrict__ whb, const float* __restrict__ wcb,
    const float* __restrict__ bih, const float* __restrict__ bhh,
    const float* __restrict__ bch, float* __restrict__ maxbuf) {
  __shared__ uint4 ldsw4[1728];      // W: 27 tiles x 1024 B (swizzled)
  __shared__ uint4 ldsx4[2 * 816];   // X: 2 slots x 13056 B
  char* ldsw = (char*)ldsw4;
  char* ldsx = (char*)ldsx4;

  const double DMI = 0.001 * 100.0;
  const double DSI = 0.001 * 200.0;
  const double S0 = 1.0 / 268435456.0;   // 2^-28

  const int tid = threadIdx.x;
  const int lane = tid & 63;
  const int wn = tid >> 6;
  const int bx = blockIdx.x;
  const int gate = bx >> 2, mq = bx & 3;
  const int rg = blockIdx.y;
  const int b = blockIdx.z;
  const int grow = gate * 64 + mq * 16;
  const int kg = lane >> 4;

  const s8* wps[3] = {W0p, W1p, W2p};

  auto xsrc = [&](int t) {
    return (const char*)X + (size_t)(t * 8 + b) * PLANE + (size_t)rg * 4 * (PADW * 64);
  };
  auto stageX = [&](int t, int slot) {
    const char* src = xsrc(t);
    char* dst = ldsx + slot * 13056;
    for (int q = tid; q < 816; q += 256) {
      int L = q << 4;
      gload16(src + (L ^ (((L >> 7) & 3) << 4)), dst + L);
    }
  };

  {  // stage W once: 27 tiles of 1024 B (16 rows x 64 ch), pre-swizzled source
    for (int g = tid; g < 1728; g += 256) {
      int tile = g >> 6;
      int L = (g & 63) << 4;
      int tap = tile / 3, part = tile - tap * 3;
      const char* src = (const char*)wps[part] + ((size_t)tap * 192 + grow) * 64
                        + (L ^ (((L >> 7) & 3) << 4));
      gload16(src, ldsw + tile * 1024 + L);
    }
  }
  stageX(0, 0); stageX(1, 1);

  // ---- per-element constants & state init (el = fn*4 + r) ----
  const int mel0 = (lane >> 4) * 4;
  const int px0 = wn * 32 + (lane & 15);
  float cterm[8];
  double v[8], cur[8];
  float mx[8], mo[8];
#pragma unroll
  for (int fn = 0; fn < 2; ++fn)
#pragma unroll
    for (int r = 0; r < 4; ++r) {
      int el = fn * 4 + r;
      int row = grow + mel0 + r;                 // 0..191
      int px = px0 + fn * 16;
      int hw = (rg * 4 + (px >> 5)) * 32 + (px & 31);
      float ct = bih[row] + bhh[row] + whb[((size_t)b * 192 + row) * 1024 + hw];
      if (gate < 2)
        ct += bch[row] + wcb[((size_t)b * 128 + row) * 1024 + hw];
      cterm[el] = ct;
      v[el] = 0.0; cur[el] = 0.0; mx[el] = -INFINITY; mo[el] = -INFINITY;
    }

  i32x4 acc[2][3][2];
#pragma unroll
  for (int t2 = 0; t2 < 2; ++t2)
#pragma unroll
    for (int p = 0; p < 3; ++p)
#pragma unroll
      for (int fn = 0; fn < 2; ++fn)
#pragma unroll
        for (int k = 0; k < 4; ++k) acc[t2][p][fn][k] = 0;

  __syncthreads();

  for (int tc = 0; tc < 16; ++tc) {
#pragma unroll
    for (int tap = 0; tap < 9; ++tap) {
      const int kh = tap / 3, kw = tap - kh * 3;
      i32x4 af[3];
#pragma unroll
      for (int p = 0; p < 3; ++p) {
        int m = lane & 15;
        int byte = (m * 64 + kg * 16) ^ (((m >> 1) & 3) << 4);
        af[p] = *reinterpret_cast<const i32x4*>(ldsw + (tap * 3 + p) * 1024 + byte);
      }
#pragma unroll
      for (int t2 = 0; t2 < 2; ++t2) {
        const char* xs = ldsx + t2 * 13056;
        i32x4 bfr[2];
#pragma unroll
        for (int fn = 0; fn < 2; ++fn) {
          int p = px0 + fn * 16;
          int pL = ((p >> 5) + kh) * PADW + (p & 31) + kw;
          int byte = (pL * 64 + kg * 16) ^ (((pL >> 1) & 3) << 4);
          bfr[fn] = *reinterpret_cast<const i32x4*>(xs + byte);
        }
        __builtin_amdgcn_s_setprio(1);
#pragma unroll
        for (int p = 0; p < 3; ++p)
#pragma unroll
          for (int fn = 0; fn < 2; ++fn)
            acc[t2][p][fn] = __builtin_amdgcn_mfma_i32_16x16x64_i8(af[p], bfr[fn], acc[t2][p][fn], 0, 0, 0);
        __builtin_amdgcn_s_setprio(0);
      }
    }
    __syncthreads();                 // all waves done reading X slots
    if (tc < 15) { stageX(2 * tc + 2, 0); stageX(2 * tc + 3, 1); }  // issue prefetch
    // ---- LIF update for t = 2tc, 2tc+1 (exact recombine, f64 states) ----
    // runs on VALU while the X prefetch is in flight
#pragma unroll
    for (int t2 = 0; t2 < 2; ++t2) {
      int t = 2 * tc + t2;
#pragma unroll
      for (int fn = 0; fn < 2; ++fn)
#pragma unroll
        for (int r = 0; r < 4; ++r) {
          int el = fn * 4 + r;
          int a0 = acc[t2][0][fn][r], a1 = acc[t2][1][fn][r], a2 = acc[t2][2][fn][r];
          double wx = ((double)a2 * 65536.0 + (double)(a1 * 256 + a0)) * S0;
          double inp = wx + (double)cterm[el];
          double vd = v[el] + DMI * (cur[el] - v[el]);   // OLD current
          double vnew = (vd > 1.0) ? 0.0 : vd;
          v[el] = vnew;
          cur[el] = (cur[el] - DSI * cur[el]) + inp;
          if (gate == 2) {
            double vod = vnew + DMI * (cur[el] - vnew);  // o-gate from UPDATED g
            double vo = (vod > 1.0) ? 0.0 : vod;
            if (t >= 1) mo[el] = fmaxf(mo[el], (float)vo);
          }
          if (t >= 1) mx[el] = fmaxf(mx[el], (float)vnew);
        }
#pragma unroll
      for (int p = 0; p < 3; ++p)
#pragma unroll
        for (int fn = 0; fn < 2; ++fn)
#pragma unroll
          for (int k = 0; k < 4; ++k) acc[t2][p][fn][k] = 0;
    }
    __syncthreads();                 // drains prefetch -> slots ready
  }

  // ---- write per-gate maxima ----
#pragma unroll
  for (int fn = 0; fn < 2; ++fn)
#pragma unroll
    for (int r = 0; r < 4; ++r) {
      int el = fn * 4 + r;
      int c = mq * 16 + mel0 + r;
      int px = px0 + fn * 16;
      int hw = (rg * 4 + (px >> 5)) * 32 + (px & 31);
      size_t e = ((size_t)b * 64 + c) * 1024 + hw;
      maxbuf[(size_t)gate * NELEM + e] = mx[el];
      if (gate == 2) maxbuf[(size_t)3 * NELEM + e] = mo[el];
    }
}

// wh + wc conv merged: bf16 3-plane x 3-part, 6 cross terms (unchanged).
__global__ __launch_bounds__(256) void conv1_kernel(
    const u16* __restrict__ Ah0, const u16* __restrict__ Ah1, const u16* __restrict__ Ah2,
    const u16* __restrict__ Ac0, const u16* __restrict__ Ac1, const u16* __restrict__ Ac2,
    const u16* __restrict__ Wh0, const u16* __restrict__ Wh1, const u16* __restrict__ Wh2,
    const u16* __restrict__ Wc0, const u16* __restrict__ Wc1, const u16* __restrict__ Wc2,
    float* __restrict__ outh, float* __restrict__ outc) {
  __shared__ uint4 ldsx4[3 * 1088];   // per plane: 4 rows x 34 px x 128 B
  __shared__ uint4 ldsw4[3 * 512];    // single buffer: 3 parts x 8 KB
  char* ldsx = (char*)ldsx4;
  char* ldsw = (char*)ldsw4;

  const int tid = threadIdx.x;
  const int lane = tid & 63;
  const int wid = tid >> 6;
  const bool isC = blockIdx.x >= 3;
  const int mtile = isC ? blockIdx.x - 3 : blockIdx.x;
  const int Mtot = isC ? 128 : 192;
  const int rg = blockIdx.y;          // 0..15 (2 px-rows each)
  const int img = blockIdx.z;
  const u16* aps[3] = {isC ? Ac0 : Ah0, isC ? Ac1 : Ah1, isC ? Ac2 : Ah2};
  const u16* wps[3] = {isC ? Wc0 : Wh0, isC ? Wc1 : Wh1, isC ? Wc2 : Wh2};
  float* out = isC ? outc : outh;

  {
    size_t abase = (size_t)img * PLANE + (size_t)rg * 2 * (PADW * 64);
#pragma unroll
    for (int pl = 0; pl < 3; ++pl) {
      const char* src = (const char*)(aps[pl] + abase);
      for (int q = tid; q < 1088; q += 256) {
        int L = q << 4;
        gload16(src + (L ^ (((L >> 7) & 7) << 4)), ldsx + pl * 17408 + L);
      }
    }
  }

  const size_t wrowbase = (size_t)mtile * 64 * 64;
  auto stageW = [&](int tap) {
#pragma unroll
    for (int part = 0; part < 3; ++part) {
      const char* gsrc = (const char*)(wps[part] + (size_t)tap * Mtot * 64 + wrowbase);
#pragma unroll
      for (int half = 0; half < 2; ++half) {
        int L = half * 4096 + tid * 16;
        gload16(gsrc + (L ^ (((L >> 7) & 7) << 4)), ldsw + part * 8192 + L);
      }
    }
  };

  f32x4 acc[2][2];
#pragma unroll
  for (int i = 0; i < 2; ++i)
#pragma unroll
    for (int j = 0; j < 2; ++j)
#pragma unroll
      for (int k = 0; k < 4; ++k) acc[i][j][k] = 0.f;

  const int wm = wid >> 1, wn = wid & 1;

  for (int tap = 0; tap < 9; ++tap) {
    if (tap) __syncthreads();
    stageW(tap);
    __syncthreads();
    const int kh = tap / 3, kw = tap - kh * 3;
#pragma unroll
    for (int khalf = 0; khalf < 2; ++khalf) {
      short8 af[3][2];
#pragma unroll
      for (int part = 0; part < 3; ++part)
#pragma unroll
        for (int fm = 0; fm < 2; ++fm) {
          int m = wm * 32 + fm * 16 + (lane & 15);
          int byte = (m * 128 + khalf * 64 + (lane >> 4) * 16) ^ ((m & 7) << 4);
          af[part][fm] = *reinterpret_cast<const short8*>(ldsw + part * 8192 + byte);
        }
#pragma unroll
      for (int pl = 0; pl < 3; ++pl) {
        short8 bfr[2];
#pragma unroll
        for (int fn = 0; fn < 2; ++fn) {
          int p = wn * 32 + fn * 16 + (lane & 15);
          int r = p >> 5, w = p & 31;
          int pL = (r + kh) * PADW + (w + kw);
          int byte = (pL * 128 + khalf * 64 + (lane >> 4) * 16) ^ ((pL & 7) << 4);
          bfr[fn] = *reinterpret_cast<const short8*>(ldsx + pl * 17408 + byte);
        }
        constexpr int npt[3] = {3, 2, 1};
        __builtin_amdgcn_s_setprio(1);
#pragma unroll
        for (int part = 0; part < 3; ++part) {
          if (part < npt[pl]) {
#pragma unroll
            for (int fm = 0; fm < 2; ++fm)
#pragma unroll
              for (int fn = 0; fn < 2; ++fn)
                acc[fm][fn] = __builtin_amdgcn_mfma_f32_16x16x32_bf16(af[part][fm], bfr[fn], acc[fm][fn], 0, 0, 0);
          }
        }
        __builtin_amdgcn_s_setprio(0);
      }
    }
  }

  size_t obase = (size_t)img * Mtot * 1024;
#pragma unroll
  for (int fm = 0; fm < 2; ++fm)
#pragma unroll
    for (int fn = 0; fn < 2; ++fn) {
      int pcol = rg * 64 + wn * 32 + fn * 16 + (lane & 15);
      int mrow0 = mtile * 64 + wm * 32 + fm * 16 + (lane >> 4) * 4;
#pragma unroll
      for (int r2 = 0; r2 < 4; ++r2)
        out[obase + (size_t)(mrow0 + r2) * 1024 + pcol] = acc[fm][fn][r2];
    }
}

__global__ void final_kernel(const float* __restrict__ maxbuf, const float* __restrict__ c0,
                             float* __restrict__ out) {
  int e = blockIdx.x * 256 + threadIdx.x;
  double mi = (double)maxbuf[e];
  double mf = (double)maxbuf[NELEM + e];
  double mg = (double)maxbuf[2 * (size_t)NELEM + e];
  double mo = (double)maxbuf[3 * (size_t)NELEM + e];
  double c1 = mf * (double)c0[e] + mi * mg;
  out[e] = (float)(mo * tanh(c1));
  out[NELEM + e] = (float)c1;
}

extern "C" void kernel_launch(void* const* d_in, const int* in_sizes, int n_in,
                              void* d_out, int out_size, void* d_ws, size_t ws_size,
                              hipStream_t stream) {
  const float* input = (const float*)d_in[0];
  const float* h0    = (const float*)d_in[1];
  const float* c0    = (const float*)d_in[2];
  const float* wih   = (const float*)d_in[3];
  const float* whh   = (const float*)d_in[4];
  const float* wch   = (const float*)d_in[5];
  const float* bih   = (const float*)d_in[6];
  const float* bhh   = (const float*)d_in[7];
  const float* bch   = (const float*)d_in[8];
  char* ws = (char*)d_ws;

  size_t off = 0;
  auto take = [&](size_t bytes) { size_t o = off; off += (bytes + 255) & ~(size_t)255; return o; };
  size_t oXp  = take((size_t)SEQ * 8 * PLANE);          // i8 spikes, 18.9 MB
  size_t oH1  = take((size_t)8 * PLANE * 2);
  size_t oH2  = take((size_t)8 * PLANE * 2);
  size_t oH3  = take((size_t)8 * PLANE * 2);
  size_t oC1  = take((size_t)8 * PLANE * 2);
  size_t oC2  = take((size_t)8 * PLANE * 2);
  size_t oC3  = take((size_t)8 * PLANE * 2);
  size_t oIq0 = take((size_t)9 * 192 * 64);             // i8 weight parts
  size_t oIq1 = take((size_t)9 * 192 * 64);
  size_t oIq2 = take((size_t)9 * 192 * 64);
  size_t oHh1 = take((size_t)9 * 192 * 64 * 2);
  size_t oHh2 = take((size_t)9 * 192 * 64 * 2);
  size_t oHh3 = take((size_t)9 * 192 * 64 * 2);
  size_t oCh1 = take((size_t)9 * 128 * 64 * 2);
  size_t oCh2 = take((size_t)9 * 128 * 64 * 2);
  size_t oCh3 = take((size_t)9 * 128 * 64 * 2);
  size_t oWh  = take((size_t)8 * 192 * 1024 * 4);
  size_t oWc  = take((size_t)8 * 128 * 1024 * 4);
  size_t oMx  = take((size_t)4 * NELEM * 4);            // maxima planes

  s8* xp   = (s8*)(ws + oXp);
  u16* h1p = (u16*)(ws + oH1); u16* h2p = (u16*)(ws + oH2); u16* h3p = (u16*)(ws + oH3);
  u16* c1p = (u16*)(ws + oC1); u16* c2p = (u16*)(ws + oC2); u16* c3p = (u16*)(ws + oC3);
  s8* iq0  = (s8*)(ws + oIq0); s8* iq1 = (s8*)(ws + oIq1); s8* iq2 = (s8*)(ws + oIq2);
  u16* hh1 = (u16*)(ws + oHh1); u16* hh2 = (u16*)(ws + oHh2); u16* hh3 = (u16*)(ws + oHh3);
  u16* ch1 = (u16*)(ws + oCh1); u16* ch2 = (u16*)(ws + oCh2); u16* ch3 = (u16*)(ws + oCh3);
  float* whb = (float*)(ws + oWh);
  float* wcb = (float*)(ws + oWc);
  float* mxb = (float*)(ws + oMx);

  encode_kernel<<<2312, 256, 0, stream>>>(input, xp);
  prep_hc_kernel<<<2312, 256, 0, stream>>>(h0, c0, h1p, h2p, h3p, c1p, c2p, c3p);
  prep_w_kernel<<<1152, 256, 0, stream>>>(wih, whh, wch, iq0, iq1, iq2,
                                          hh1, hh2, hh3, ch1, ch2, ch3);

  conv1_kernel<<<dim3(5, 16, 8), 256, 0, stream>>>(
      h1p, h2p, h3p, c1p, c2p, c3p,
      hh1, hh2, hh3, ch1, ch2, ch3, whb, wcb);

  fused_kernel<<<dim3(12, 8, 8), 256, 0, stream>>>(
      xp, iq0, iq1, iq2, whb, wcb, bih, bhh, bch, mxb);

  final_kernel<<<2048, 256, 0, stream>>>(mxb, c0, (float*)d_out);
}